// Round 5
// baseline (441.595 us; speedup 1.0000x reference)
//
#include <hip/hip_runtime.h>

#define DECAY 0.99f
#define ONE_MINUS_DECAY 0.01f
#define EPSF 1e-5f
#define BETA 0.25f
#define TAU 1e-2f

constexpr int M_ = 32768;            // rows (B*H*W)
constexpr int N_ = 1024;             // codes
constexpr int K_ = 128;              // dim

typedef _Float16 f16;
typedef f16 f16x8 __attribute__((ext_vector_type(8)));
typedef float f32x4 __attribute__((ext_vector_type(4)));

#define GLOAD_LDS(g, l) __builtin_amdgcn_global_load_lds( \
    (const __attribute__((address_space(1))) void*)(g),   \
    (__attribute__((address_space(3))) void*)(l), 16, 0, 0)

// ---- workspace layout (bytes) ----
constexpr size_t WS_FLAT   = 0;                                   // M*K fp32 (16MB)
constexpr size_t WS_XH     = WS_FLAT   + (size_t)M_ * K_ * 4;     // M*K f16, tile-swizzled (8MB)
constexpr size_t WS_XL     = WS_XH     + (size_t)M_ * K_ * 2;     // M*K f16 (8MB)
constexpr size_t WS_EH     = WS_XL     + (size_t)M_ * K_ * 2;     // N*K f16 (-2e hi)
constexpr size_t WS_EL     = WS_EH     + (size_t)N_ * K_ * 2;     // N*K f16 (-2e lo)
constexpr size_t WS_NL     = WS_EL     + (size_t)N_ * K_ * 2;     // N fp32 ||e||^2
constexpr size_t WS_P1     = WS_NL     + (size_t)N_ * 4;          // 4*M f32 best score
constexpr size_t WS_PI1    = WS_P1     + (size_t)4 * M_ * 4;      // 4*M int best idx
constexpr size_t WS_P2     = WS_PI1    + (size_t)4 * M_ * 4;      // 4*M f32 2nd score
constexpr size_t WS_PI2    = WS_P2     + (size_t)4 * M_ * 4;      // 4*M int 2nd idx
constexpr size_t WS_IDX    = WS_PI2    + (size_t)4 * M_ * 4;      // M int
constexpr size_t WS_COUNTS = WS_IDX    + (size_t)M_ * 4;          // N int (zeroed)
constexpr size_t WS_CUR    = WS_COUNTS + (size_t)N_ * 4;          // N int (zeroed)
constexpr size_t WS_OFFS   = WS_CUR    + (size_t)N_ * 4;          // N int
constexpr size_t WS_ROWS   = WS_OFFS   + (size_t)N_ * 4;          // M int
constexpr size_t WS_LPART  = WS_ROWS   + (size_t)M_ * 4;          // 4096 doubles
constexpr size_t WS_NSUM   = WS_LPART  + (size_t)4096 * 8;        // 1 float
constexpr size_t ZERO_OFF  = WS_COUNTS;
constexpr size_t ZERO_LEN  = WS_OFFS - WS_COUNTS;                 // counts + cur

// ---- output layout (float elements) ----
constexpr size_t O_ZQST = 0;
constexpr size_t O_LOSS = O_ZQST + (size_t)M_ * K_;
constexpr size_t O_IDX  = O_LOSS + 1;
constexpr size_t O_ZQ   = O_IDX  + (size_t)M_;
constexpr size_t O_ZE   = O_ZQ   + (size_t)M_ * K_;
constexpr size_t O_EMB  = O_ZE   + (size_t)M_ * K_;
constexpr size_t O_NCS  = O_EMB  + (size_t)N_ * K_;
constexpr size_t O_NEA  = O_NCS  + (size_t)N_;

// ||e||^2 + hi/lo fp16 split of (-2e)
__global__ void ecvt_kernel(const float* __restrict__ embed,
                            f16* __restrict__ eh, f16* __restrict__ el,
                            float* __restrict__ nl) {
    int j = blockIdx.x, lane = threadIdx.x;          // 64 threads
    const float* e = embed + (size_t)j * K_;
    float a = e[lane], b = e[lane + 64];
    float s = a * a + b * b;
    #pragma unroll
    for (int off = 32; off; off >>= 1) s += __shfl_down(s, off);
    if (lane == 0) nl[j] = s;
    float ma = -2.f * a, mb = -2.f * b;
    f16 ah = (f16)ma, bh2 = (f16)mb;
    eh[(size_t)j * K_ + lane] = ah;
    eh[(size_t)j * K_ + lane + 64] = bh2;
    el[(size_t)j * K_ + lane] = (f16)(ma - (float)ah);
    el[(size_t)j * K_ + lane + 64] = (f16)(mb - (float)bh2);
}

// (B,C,H,W) -> flat[r][c] fp32 + xh/xl f16 in tile-swizzled layout + z_e out.
// xh addr: r*128 + ((c/8 ^ (r&15))*8) + c%8  == per-64-row-tile LDS image.
__global__ void transpose_kernel(const float* __restrict__ ze,
                                 float* __restrict__ flat,
                                 f16* __restrict__ xh, f16* __restrict__ xl,
                                 float* __restrict__ out_ze) {
    __shared__ float tile[128][33];
    int b = blockIdx.x >> 5, h = blockIdx.x & 31;
    const size_t base = (size_t)b * 131072 + (size_t)h * 32;
    int t = threadIdx.x;
    #pragma unroll
    for (int i = 0; i < 16; ++i) {
        int q = i * 256 + t;
        int c = q >> 5, w = q & 31;
        float v = ze[base + (size_t)c * 1024 + w];
        tile[c][w] = v;
        out_ze[base + (size_t)c * 1024 + w] = v;
    }
    __syncthreads();
    const int r0 = b * 1024 + h * 32;
    #pragma unroll
    for (int i = 0; i < 16; ++i) {
        int q = i * 256 + t;
        int c = q & 127, w = q >> 7;
        float v = tile[c][w];
        int r = r0 + w;
        flat[(size_t)r * K_ + c] = v;
        f16 hh = (f16)v;
        f16 ll = (f16)(v - (float)hh);
        size_t xa = (size_t)r * K_ + ((((c >> 3) ^ (r & 15)) << 3) | (c & 7));
        xh[xa] = hh;
        xl[xa] = ll;
    }
}

// MFMA NN search. Grid (128,4): y = 256-code split; 4 waves each own 64 codes
// as persistent A-frags (f16 hi+lo of -2e). x tiles (64 rows) streamed via
// global_load_lds from the pre-swizzled xh/xl images, double-buffered.
// d = ||e||^2 - 2 x.e via 3 MFMAs; per-row top-2, near-ties refined exactly.
__global__ __launch_bounds__(256, 2)
void nn_kernel(const f16* __restrict__ xh_g, const f16* __restrict__ xl_g,
               const f16* __restrict__ eh, const f16* __restrict__ el,
               const float* __restrict__ nl,
               float* __restrict__ p1, int* __restrict__ pi1,
               float* __restrict__ p2, int* __restrict__ pi2) {
    __shared__ __align__(16) f16 xb[2][2][64 * 128];   // [dbuf][hi/lo] 64KB
    __shared__ float rsc[4][64], rs2[4][64];
    __shared__ int   ric[4][64], ri2[4][64];
    const int t = threadIdx.x;
    const int wave = t >> 6, lane = t & 63;
    const int crow = lane & 15, g = lane >> 4;
    const int c0 = blockIdx.y * 256 + wave * 64;

    f16x8 efh[4][4], efl[4][4];          // [code-mtile][ktile]
    #pragma unroll
    for (int m = 0; m < 4; ++m)
        #pragma unroll
        for (int kt = 0; kt < 4; ++kt) {
            size_t eo = (size_t)(c0 + m * 16 + crow) * K_ + kt * 32 + g * 8;
            efh[m][kt] = *(const f16x8*)(eh + eo);
            efl[m][kt] = *(const f16x8*)(el + eo);
        }
    f32x4 nlv[4];
    #pragma unroll
    for (int m = 0; m < 4; ++m)
        nlv[m] = *(const f32x4*)(nl + c0 + m * 16 + g * 4);

    auto stage = [&](int bt, int db) {
        const size_t tb = (size_t)(blockIdx.x * 4 + bt) * 8192;
        #pragma unroll
        for (int i = 0; i < 4; ++i) {
            int q = wave * 4 + i;                       // 16 x 1KB chunks
            GLOAD_LDS(xh_g + tb + q * 512 + lane * 8, &xb[db][0][q * 512]);
            GLOAD_LDS(xl_g + tb + q * 512 + lane * 8, &xb[db][1][q * 512]);
        }
    };

    stage(0, 0);
    for (int bt = 0; bt < 4; ++bt) {
        const int db = bt & 1;
        __syncthreads();                  // drains vmcnt: tile bt ready; merge bt-1 done
        if (bt < 3) stage(bt + 1, db ^ 1);
        #pragma unroll
        for (int st = 0; st < 4; ++st) {
            f32x4 acc[4];
            #pragma unroll
            for (int m = 0; m < 4; ++m) acc[m] = (f32x4){0.f, 0.f, 0.f, 0.f};
            #pragma unroll
            for (int kt = 0; kt < 4; ++kt) {
                int off = (st * 16 + crow) * 128 + ((((kt << 2) + g) ^ crow) << 3);
                f16x8 bh = *(const f16x8*)&xb[db][0][off];
                f16x8 bl = *(const f16x8*)&xb[db][1][off];
                #pragma unroll
                for (int m = 0; m < 4; ++m) {
                    acc[m] = __builtin_amdgcn_mfma_f32_16x16x32_f16(efh[m][kt], bh, acc[m], 0, 0, 0);
                    acc[m] = __builtin_amdgcn_mfma_f32_16x16x32_f16(efl[m][kt], bh, acc[m], 0, 0, 0);
                    acc[m] = __builtin_amdgcn_mfma_f32_16x16x32_f16(efh[m][kt], bl, acc[m], 0, 0, 0);
                }
            }
            float b1 = 3.4e38f, b2 = 3.4e38f; int i1 = -1, i2 = -1;
            #pragma unroll
            for (int m = 0; m < 4; ++m)
                #pragma unroll
                for (int q = 0; q < 4; ++q) {
                    float s = acc[m][q] + nlv[m][q];
                    int c = c0 + m * 16 + g * 4 + q;
                    if (s < b1) { b2 = b1; i2 = i1; b1 = s; i1 = c; }
                    else if (s < b2 || (s == b2 && c < i2)) { b2 = s; i2 = c; }
                }
            #pragma unroll
            for (int d = 16; d <= 32; d <<= 1) {
                float ob1 = __shfl_xor(b1, d); int oi1 = __shfl_xor(i1, d);
                float ob2 = __shfl_xor(b2, d); int oi2 = __shfl_xor(i2, d);
                bool o_lt = (ob1 < b1) || (ob1 == b1 && oi1 < i1);
                float w2 = o_lt ? ob2 : b2; int wi2 = o_lt ? oi2 : i2;
                float l1 = o_lt ? b1 : ob1; int li1 = o_lt ? i1 : oi1;
                if (o_lt) { b1 = ob1; i1 = oi1; }
                bool s_lt = (l1 < w2) || (l1 == w2 && li1 < wi2);
                b2 = s_lt ? l1 : w2; i2 = s_lt ? li1 : wi2;
            }
            if (lane < 16) {
                int rr = st * 16 + crow;
                rsc[wave][rr] = b1; ric[wave][rr] = i1;
                rs2[wave][rr] = b2; ri2[wave][rr] = i2;
            }
        }
        __syncthreads();
        if (t < 64) {                     // merge 4 waves -> one partial set per y
            float b1 = rsc[0][t], b2 = rs2[0][t];
            int i1 = ric[0][t], i2 = ri2[0][t];
            #pragma unroll
            for (int w = 1; w < 4; ++w) {
                float ob1 = rsc[w][t]; int oi1 = ric[w][t];
                float ob2 = rs2[w][t]; int oi2 = ri2[w][t];
                bool o_lt = (ob1 < b1) || (ob1 == b1 && oi1 < i1);
                float w2 = o_lt ? ob2 : b2; int wi2 = o_lt ? oi2 : i2;
                float l1 = o_lt ? b1 : ob1; int li1 = o_lt ? i1 : oi1;
                if (o_lt) { b1 = ob1; i1 = oi1; }
                bool s_lt = (l1 < w2) || (l1 == w2 && li1 < wi2);
                b2 = s_lt ? l1 : w2; i2 = s_lt ? li1 : wi2;
            }
            size_t o = (size_t)blockIdx.y * M_ + (blockIdx.x * 4 + bt) * 64 + t;
            p1[o] = b1; pi1[o] = i1; p2[o] = b2; pi2[o] = i2;
        }
    }
}

// merge 4 split-partials; exact fp32 refine of near-ties; counts histogram
__global__ void reduce_refine_kernel(const float* __restrict__ p1, const int* __restrict__ pi1,
                                     const float* __restrict__ p2, const int* __restrict__ pi2,
                                     const float* __restrict__ flat, const float* __restrict__ embed,
                                     const float* __restrict__ nl,
                                     int* __restrict__ idxws, float* __restrict__ out_idx,
                                     int* __restrict__ counts) {
    int r = blockIdx.x * 256 + threadIdx.x;
    float b1 = 3.4e38f, b2 = 3.4e38f; int i1 = -1, i2 = -1;
    #pragma unroll
    for (int s = 0; s < 4; ++s) {
        size_t o = (size_t)s * M_ + r;
        float ob1 = p1[o]; int oi1 = pi1[o];
        float ob2 = p2[o]; int oi2 = pi2[o];
        bool o_lt = (ob1 < b1) || (ob1 == b1 && oi1 < i1);
        float w2 = o_lt ? ob2 : b2; int wi2 = o_lt ? oi2 : i2;
        float l1 = o_lt ? b1 : ob1; int li1 = o_lt ? i1 : oi1;
        if (o_lt) { b1 = ob1; i1 = oi1; }
        bool s_lt = (l1 < w2) || (l1 == w2 && li1 < wi2);
        b2 = s_lt ? l1 : w2; i2 = s_lt ? li1 : wi2;
    }
    if (b2 - b1 < TAU) {
        const float* x  = flat  + (size_t)r * K_;
        const float* ea = embed + (size_t)i1 * K_;
        const float* eb = embed + (size_t)i2 * K_;
        float da = 0.f, db = 0.f;
        for (int k = 0; k < K_; ++k) { da = fmaf(x[k], ea[k], da); db = fmaf(x[k], eb[k], db); }
        float s1 = fmaf(-2.f, da, nl[i1]);
        float s2 = fmaf(-2.f, db, nl[i2]);
        if (s2 < s1 || (s2 == s1 && i2 < i1)) i1 = i2;
    }
    idxws[r] = i1;
    out_idx[r] = (float)i1;
    atomicAdd(counts + i1, 1);
}

// output-layout gather, 4 elems/thread: z_q_st, z_q, per-block loss partial
__global__ void gather_kernel(const float* __restrict__ ze,
                              const float* __restrict__ embed,
                              const int* __restrict__ idxws,
                              float* __restrict__ out_st, float* __restrict__ out_zq,
                              double* __restrict__ lpart) {
    int q = blockIdx.x * 256 + threadIdx.x;
    int o0 = q * 4;
    float4 zev = *(const float4*)(ze + o0);
    const float zv[4] = {zev.x, zev.y, zev.z, zev.w};
    float st4[4], zq4[4];
    double ls = 0.0;
    #pragma unroll
    for (int e = 0; e < 4; ++e) {
        int o = o0 + e;
        int r = (o >> 17) * 1024 + (o & 1023);
        int c = (o >> 10) & 127;
        int j = idxws[r];
        float zq = embed[(size_t)j * K_ + c];
        float st = zv[e] + (zq - zv[e]);
        st4[e] = st; zq4[e] = zq;
        float diff = st - zv[e];
        ls += (double)diff * (double)diff;
    }
    *(float4*)(out_st + o0) = make_float4(st4[0], st4[1], st4[2], st4[3]);
    *(float4*)(out_zq + o0) = make_float4(zq4[0], zq4[1], zq4[2], zq4[3]);
    __shared__ double red[256];
    red[threadIdx.x] = ls;
    __syncthreads();
    for (int s = 128; s; s >>= 1) {
        if (threadIdx.x < s) red[threadIdx.x] += red[threadIdx.x + s];
        __syncthreads();
    }
    if (threadIdx.x == 0) lpart[blockIdx.x] = red[0];
}

// new_cluster_size + its sum + loss + exclusive scan of counts (bucket offsets)
__global__ void ema_a_kernel(const float* __restrict__ cluster_size,
                             const int* __restrict__ counts,
                             float* __restrict__ out_ncs, float* __restrict__ nws,
                             const double* __restrict__ lpart, float* __restrict__ out_loss,
                             int* __restrict__ offs) {
    int j = threadIdx.x;                       // 1024 threads
    int cnt = counts[j];
    float ncs = cluster_size[j] * DECAY + ONE_MINUS_DECAY * (float)cnt;
    out_ncs[j] = ncs;
    __shared__ float red[1024];
    __shared__ double dred[1024];
    __shared__ int sc[1024];
    red[j] = ncs;
    sc[j] = cnt;
    double s = 0.0;
    #pragma unroll
    for (int i = 0; i < 4; ++i) s += lpart[j * 4 + i];
    dred[j] = s;
    __syncthreads();
    for (int d = 1; d < 1024; d <<= 1) {       // Hillis-Steele inclusive scan
        int v = (j >= d) ? sc[j - d] : 0;
        __syncthreads();
        sc[j] += v;
        __syncthreads();
    }
    offs[j] = sc[j] - cnt;
    for (int st = 512; st; st >>= 1) {
        if (j < st) { red[j] += red[j + st]; dred[j] += dred[j + st]; }
        __syncthreads();
    }
    if (j == 0) {
        nws[0] = red[0];
        out_loss[0] = (float)((double)BETA * (dred[0] / 4194304.0));
    }
}

// scatter row ids into per-code buckets
__global__ void bucket_kernel(const int* __restrict__ idxws, const int* __restrict__ offs,
                              int* __restrict__ cur, int* __restrict__ rows) {
    int r = blockIdx.x * 256 + threadIdx.x;
    int j = idxws[r];
    int pos = atomicAdd(cur + j, 1);
    rows[offs[j] + pos] = r;
}

// per-code gather-sum of flat rows + full EMA epilogue (replaces scatter+ema_b)
__global__ void codesum_kernel(const float* __restrict__ flat, const int* __restrict__ rows,
                               const int* __restrict__ offs, const int* __restrict__ counts,
                               const float* __restrict__ embed_avg,
                               const float* __restrict__ out_ncs, const float* __restrict__ nws,
                               float* __restrict__ out_nea, float* __restrict__ out_emb) {
    int j = blockIdx.x, k = threadIdx.x;       // 1024 blocks x 128 threads
    int cnt = counts[j], base = offs[j];
    float acc = 0.f;
    for (int i = 0; i < cnt; ++i) {
        int rid = rows[base + i];
        acc += flat[(size_t)rid * K_ + k];
    }
    size_t o = (size_t)j * K_ + k;
    float navg = embed_avg[o] * DECAY + ONE_MINUS_DECAY * acc;
    out_nea[o] = navg;
    float n = nws[0];
    float denom = n + 1024.0f * EPSF;
    float cs = (out_ncs[j] + EPSF) / denom * n;
    float cs_safe = fmaxf(cs, EPSF);
    float v = navg / cs_safe;
    if (v != v) v = 0.f;
    v = fminf(fmaxf(v, -2.f), 2.f);
    out_emb[o] = v;
}

extern "C" void kernel_launch(void* const* d_in, const int* in_sizes, int n_in,
                              void* d_out, int out_size, void* d_ws, size_t ws_size,
                              hipStream_t stream) {
    const float* z_e          = (const float*)d_in[0];
    const float* embed        = (const float*)d_in[1];
    const float* cluster_size = (const float*)d_in[2];
    const float* embed_avg    = (const float*)d_in[3];
    float* out = (float*)d_out;
    char*  ws  = (char*)d_ws;

    float*  flat   = (float*)(ws + WS_FLAT);
    f16*    xhp    = (f16*)  (ws + WS_XH);
    f16*    xlp    = (f16*)  (ws + WS_XL);
    f16*    ehp    = (f16*)  (ws + WS_EH);
    f16*    elp    = (f16*)  (ws + WS_EL);
    float*  nlp    = (float*)(ws + WS_NL);
    float*  p1     = (float*)(ws + WS_P1);
    int*    pi1    = (int*)  (ws + WS_PI1);
    float*  p2     = (float*)(ws + WS_P2);
    int*    pi2    = (int*)  (ws + WS_PI2);
    int*    idxws  = (int*)  (ws + WS_IDX);
    int*    counts = (int*)  (ws + WS_COUNTS);
    int*    cur    = (int*)  (ws + WS_CUR);
    int*    offs   = (int*)  (ws + WS_OFFS);
    int*    rows   = (int*)  (ws + WS_ROWS);
    double* lpart  = (double*)(ws + WS_LPART);
    float*  nws    = (float*)(ws + WS_NSUM);

    hipMemsetAsync(ws + ZERO_OFF, 0, ZERO_LEN, stream);

    ecvt_kernel<<<N_, 64, 0, stream>>>(embed, ehp, elp, nlp);
    transpose_kernel<<<1024, 256, 0, stream>>>(z_e, flat, xhp, xlp, out + O_ZE);
    nn_kernel<<<dim3(128, 4), 256, 0, stream>>>(xhp, xlp, ehp, elp, nlp, p1, pi1, p2, pi2);
    reduce_refine_kernel<<<M_ / 256, 256, 0, stream>>>(p1, pi1, p2, pi2, flat, embed, nlp,
                                                       idxws, out + O_IDX, counts);
    gather_kernel<<<4096, 256, 0, stream>>>(z_e, embed, idxws,
                                            out + O_ZQST, out + O_ZQ, lpart);
    ema_a_kernel<<<1, 1024, 0, stream>>>(cluster_size, counts, out + O_NCS, nws,
                                         lpart, out + O_LOSS, offs);
    bucket_kernel<<<M_ / 256, 256, 0, stream>>>(idxws, offs, cur, rows);
    codesum_kernel<<<N_, K_, 0, stream>>>(flat, rows, offs, counts, embed_avg,
                                          out + O_NCS, nws, out + O_NEA, out + O_EMB);
}

// Round 6
// 126.614 us; speedup vs baseline: 3.4877x; 3.4877x over previous
//
#include <hip/hip_runtime.h>

#define DECAY 0.99f
#define ONE_MINUS_DECAY 0.01f
#define EPSF 1e-5f
#define BETA 0.25f
#define TAU 1e-2f

constexpr int M_ = 32768;            // rows (B*H*W)
constexpr int N_ = 1024;             // codes
constexpr int K_ = 128;              // dim

typedef _Float16 f16;
typedef f16 f16x8 __attribute__((ext_vector_type(8)));
typedef float f32x4 __attribute__((ext_vector_type(4)));

#define GLOAD_LDS(g, l) __builtin_amdgcn_global_load_lds( \
    (const __attribute__((address_space(1))) void*)(g),   \
    (__attribute__((address_space(3))) void*)(l), 16, 0, 0)

// ---- workspace layout (bytes) ----
constexpr size_t WS_FLAT   = 0;                                   // M*K fp32 (16MB)
constexpr size_t WS_XH     = WS_FLAT   + (size_t)M_ * K_ * 4;     // M*K f16, tile-swizzled
constexpr size_t WS_XL     = WS_XH     + (size_t)M_ * K_ * 2;     // M*K f16
constexpr size_t WS_EH     = WS_XL     + (size_t)M_ * K_ * 2;     // N*K f16 (-2e hi)
constexpr size_t WS_EL     = WS_EH     + (size_t)N_ * K_ * 2;     // N*K f16 (-2e lo)
constexpr size_t WS_NL     = WS_EL     + (size_t)N_ * K_ * 2;     // N fp32 ||e||^2
constexpr size_t WS_P1     = WS_NL     + (size_t)N_ * 4;          // 4*M f32 best score
constexpr size_t WS_PI1    = WS_P1     + (size_t)4 * M_ * 4;      // 4*M int best idx
constexpr size_t WS_P2     = WS_PI1    + (size_t)4 * M_ * 4;      // 4*M f32 2nd score
constexpr size_t WS_PI2    = WS_P2     + (size_t)4 * M_ * 4;      // 4*M int 2nd idx
constexpr size_t WS_IDX    = WS_PI2    + (size_t)4 * M_ * 4;      // M int
constexpr size_t WS_COUNTS = WS_IDX    + (size_t)M_ * 4;          // N int   (zeroed)
constexpr size_t WS_CUR    = WS_COUNTS + (size_t)N_ * 4;          // N int   (zeroed)
constexpr size_t WS_ESUM   = WS_CUR    + (size_t)N_ * 4;          // N*K f32 (zeroed)
constexpr size_t WS_OFFS   = WS_ESUM   + (size_t)N_ * K_ * 4;     // N int
constexpr size_t WS_ROWS   = WS_OFFS   + (size_t)N_ * 4;          // M int
constexpr size_t WS_LPART  = WS_ROWS   + (size_t)M_ * 4;          // 4096 doubles
constexpr size_t WS_NSUM   = WS_LPART  + (size_t)4096 * 8;        // 1 float
constexpr size_t ZERO_OFF  = WS_COUNTS;
constexpr size_t ZERO_LEN  = WS_OFFS - WS_COUNTS;                 // counts + cur + esum

// ---- output layout (float elements) ----
constexpr size_t O_ZQST = 0;
constexpr size_t O_LOSS = O_ZQST + (size_t)M_ * K_;
constexpr size_t O_IDX  = O_LOSS + 1;
constexpr size_t O_ZQ   = O_IDX  + (size_t)M_;
constexpr size_t O_ZE   = O_ZQ   + (size_t)M_ * K_;
constexpr size_t O_EMB  = O_ZE   + (size_t)M_ * K_;
constexpr size_t O_NCS  = O_EMB  + (size_t)N_ * K_;
constexpr size_t O_NEA  = O_NCS  + (size_t)N_;

// ||e||^2 + hi/lo fp16 split of (-2e)
__global__ void ecvt_kernel(const float* __restrict__ embed,
                            f16* __restrict__ eh, f16* __restrict__ el,
                            float* __restrict__ nl) {
    int j = blockIdx.x, lane = threadIdx.x;          // 64 threads
    const float* e = embed + (size_t)j * K_;
    float a = e[lane], b = e[lane + 64];
    float s = a * a + b * b;
    #pragma unroll
    for (int off = 32; off; off >>= 1) s += __shfl_down(s, off);
    if (lane == 0) nl[j] = s;
    float ma = -2.f * a, mb = -2.f * b;
    f16 ah = (f16)ma, bh2 = (f16)mb;
    eh[(size_t)j * K_ + lane] = ah;
    eh[(size_t)j * K_ + lane + 64] = bh2;
    el[(size_t)j * K_ + lane] = (f16)(ma - (float)ah);
    el[(size_t)j * K_ + lane + 64] = (f16)(mb - (float)bh2);
}

// (B,C,H,W) -> flat[r][c] fp32 + xh/xl f16 in tile-swizzled layout + z_e out.
__global__ void transpose_kernel(const float* __restrict__ ze,
                                 float* __restrict__ flat,
                                 f16* __restrict__ xh, f16* __restrict__ xl,
                                 float* __restrict__ out_ze) {
    __shared__ float tile[128][33];
    int b = blockIdx.x >> 5, h = blockIdx.x & 31;
    const size_t base = (size_t)b * 131072 + (size_t)h * 32;
    int t = threadIdx.x;
    #pragma unroll
    for (int i = 0; i < 16; ++i) {
        int q = i * 256 + t;
        int c = q >> 5, w = q & 31;
        float v = ze[base + (size_t)c * 1024 + w];
        tile[c][w] = v;
        out_ze[base + (size_t)c * 1024 + w] = v;
    }
    __syncthreads();
    const int r0 = b * 1024 + h * 32;
    #pragma unroll
    for (int i = 0; i < 16; ++i) {
        int q = i * 256 + t;
        int c = q & 127, w = q >> 7;
        float v = tile[c][w];
        int r = r0 + w;
        flat[(size_t)r * K_ + c] = v;
        f16 hh = (f16)v;
        f16 ll = (f16)(v - (float)hh);
        size_t xa = (size_t)r * K_ + ((((c >> 3) ^ (r & 15)) << 3) | (c & 7));
        xh[xa] = hh;
        xl[xa] = ll;
    }
}

// MFMA NN search (unchanged from round 5).
__global__ __launch_bounds__(256, 2)
void nn_kernel(const f16* __restrict__ xh_g, const f16* __restrict__ xl_g,
               const f16* __restrict__ eh, const f16* __restrict__ el,
               const float* __restrict__ nl,
               float* __restrict__ p1, int* __restrict__ pi1,
               float* __restrict__ p2, int* __restrict__ pi2) {
    __shared__ __align__(16) f16 xb[2][2][64 * 128];   // [dbuf][hi/lo] 64KB
    __shared__ float rsc[4][64], rs2[4][64];
    __shared__ int   ric[4][64], ri2[4][64];
    const int t = threadIdx.x;
    const int wave = t >> 6, lane = t & 63;
    const int crow = lane & 15, g = lane >> 4;
    const int c0 = blockIdx.y * 256 + wave * 64;

    f16x8 efh[4][4], efl[4][4];          // [code-mtile][ktile]
    #pragma unroll
    for (int m = 0; m < 4; ++m)
        #pragma unroll
        for (int kt = 0; kt < 4; ++kt) {
            size_t eo = (size_t)(c0 + m * 16 + crow) * K_ + kt * 32 + g * 8;
            efh[m][kt] = *(const f16x8*)(eh + eo);
            efl[m][kt] = *(const f16x8*)(el + eo);
        }
    f32x4 nlv[4];
    #pragma unroll
    for (int m = 0; m < 4; ++m)
        nlv[m] = *(const f32x4*)(nl + c0 + m * 16 + g * 4);

    auto stage = [&](int bt, int db) {
        const size_t tb = (size_t)(blockIdx.x * 4 + bt) * 8192;
        #pragma unroll
        for (int i = 0; i < 4; ++i) {
            int q = wave * 4 + i;                       // 16 x 1KB chunks
            GLOAD_LDS(xh_g + tb + q * 512 + lane * 8, &xb[db][0][q * 512]);
            GLOAD_LDS(xl_g + tb + q * 512 + lane * 8, &xb[db][1][q * 512]);
        }
    };

    stage(0, 0);
    for (int bt = 0; bt < 4; ++bt) {
        const int db = bt & 1;
        __syncthreads();                  // drains vmcnt: tile bt ready; merge bt-1 done
        if (bt < 3) stage(bt + 1, db ^ 1);
        #pragma unroll
        for (int st = 0; st < 4; ++st) {
            f32x4 acc[4];
            #pragma unroll
            for (int m = 0; m < 4; ++m) acc[m] = (f32x4){0.f, 0.f, 0.f, 0.f};
            #pragma unroll
            for (int kt = 0; kt < 4; ++kt) {
                int off = (st * 16 + crow) * 128 + ((((kt << 2) + g) ^ crow) << 3);
                f16x8 bh = *(const f16x8*)&xb[db][0][off];
                f16x8 bl = *(const f16x8*)&xb[db][1][off];
                #pragma unroll
                for (int m = 0; m < 4; ++m) {
                    acc[m] = __builtin_amdgcn_mfma_f32_16x16x32_f16(efh[m][kt], bh, acc[m], 0, 0, 0);
                    acc[m] = __builtin_amdgcn_mfma_f32_16x16x32_f16(efl[m][kt], bh, acc[m], 0, 0, 0);
                    acc[m] = __builtin_amdgcn_mfma_f32_16x16x32_f16(efh[m][kt], bl, acc[m], 0, 0, 0);
                }
            }
            float b1 = 3.4e38f, b2 = 3.4e38f; int i1 = -1, i2 = -1;
            #pragma unroll
            for (int m = 0; m < 4; ++m)
                #pragma unroll
                for (int q = 0; q < 4; ++q) {
                    float s = acc[m][q] + nlv[m][q];
                    int c = c0 + m * 16 + g * 4 + q;
                    if (s < b1) { b2 = b1; i2 = i1; b1 = s; i1 = c; }
                    else if (s < b2 || (s == b2 && c < i2)) { b2 = s; i2 = c; }
                }
            #pragma unroll
            for (int d = 16; d <= 32; d <<= 1) {
                float ob1 = __shfl_xor(b1, d); int oi1 = __shfl_xor(i1, d);
                float ob2 = __shfl_xor(b2, d); int oi2 = __shfl_xor(i2, d);
                bool o_lt = (ob1 < b1) || (ob1 == b1 && oi1 < i1);
                float w2 = o_lt ? ob2 : b2; int wi2 = o_lt ? oi2 : i2;
                float l1 = o_lt ? b1 : ob1; int li1 = o_lt ? i1 : oi1;
                if (o_lt) { b1 = ob1; i1 = oi1; }
                bool s_lt = (l1 < w2) || (l1 == w2 && li1 < wi2);
                b2 = s_lt ? l1 : w2; i2 = s_lt ? li1 : wi2;
            }
            if (lane < 16) {
                int rr = st * 16 + crow;
                rsc[wave][rr] = b1; ric[wave][rr] = i1;
                rs2[wave][rr] = b2; ri2[wave][rr] = i2;
            }
        }
        __syncthreads();
        if (t < 64) {                     // merge 4 waves -> one partial set per y
            float b1 = rsc[0][t], b2 = rs2[0][t];
            int i1 = ric[0][t], i2 = ri2[0][t];
            #pragma unroll
            for (int w = 1; w < 4; ++w) {
                float ob1 = rsc[w][t]; int oi1 = ric[w][t];
                float ob2 = rs2[w][t]; int oi2 = ri2[w][t];
                bool o_lt = (ob1 < b1) || (ob1 == b1 && oi1 < i1);
                float w2 = o_lt ? ob2 : b2; int wi2 = o_lt ? oi2 : i2;
                float l1 = o_lt ? b1 : ob1; int li1 = o_lt ? i1 : oi1;
                if (o_lt) { b1 = ob1; i1 = oi1; }
                bool s_lt = (l1 < w2) || (l1 == w2 && li1 < wi2);
                b2 = s_lt ? l1 : w2; i2 = s_lt ? li1 : wi2;
            }
            size_t o = (size_t)blockIdx.y * M_ + (blockIdx.x * 4 + bt) * 64 + t;
            p1[o] = b1; pi1[o] = i1; p2[o] = b2; pi2[o] = i2;
        }
    }
}

// merge 4 split-partials; exact fp32 refine of near-ties; counts histogram
__global__ void reduce_refine_kernel(const float* __restrict__ p1, const int* __restrict__ pi1,
                                     const float* __restrict__ p2, const int* __restrict__ pi2,
                                     const float* __restrict__ flat, const float* __restrict__ embed,
                                     const float* __restrict__ nl,
                                     int* __restrict__ idxws, float* __restrict__ out_idx,
                                     int* __restrict__ counts) {
    int r = blockIdx.x * 256 + threadIdx.x;
    float b1 = 3.4e38f, b2 = 3.4e38f; int i1 = -1, i2 = -1;
    #pragma unroll
    for (int s = 0; s < 4; ++s) {
        size_t o = (size_t)s * M_ + r;
        float ob1 = p1[o]; int oi1 = pi1[o];
        float ob2 = p2[o]; int oi2 = pi2[o];
        bool o_lt = (ob1 < b1) || (ob1 == b1 && oi1 < i1);
        float w2 = o_lt ? ob2 : b2; int wi2 = o_lt ? oi2 : i2;
        float l1 = o_lt ? b1 : ob1; int li1 = o_lt ? i1 : oi1;
        if (o_lt) { b1 = ob1; i1 = oi1; }
        bool s_lt = (l1 < w2) || (l1 == w2 && li1 < wi2);
        b2 = s_lt ? l1 : w2; i2 = s_lt ? li1 : wi2;
    }
    if (b2 - b1 < TAU) {
        const float* x  = flat  + (size_t)r * K_;
        const float* ea = embed + (size_t)i1 * K_;
        const float* eb = embed + (size_t)i2 * K_;
        float da = 0.f, db = 0.f;
        for (int k = 0; k < K_; ++k) { da = fmaf(x[k], ea[k], da); db = fmaf(x[k], eb[k], db); }
        float s1 = fmaf(-2.f, da, nl[i1]);
        float s2 = fmaf(-2.f, db, nl[i2]);
        if (s2 < s1 || (s2 == s1 && i2 < i1)) i1 = i2;
    }
    idxws[r] = i1;
    out_idx[r] = (float)i1;
    atomicAdd(counts + i1, 1);
}

// output-layout gather, 4 elems/thread: z_q_st, z_q, per-block loss partial
__global__ void gather_kernel(const float* __restrict__ ze,
                              const float* __restrict__ embed,
                              const int* __restrict__ idxws,
                              float* __restrict__ out_st, float* __restrict__ out_zq,
                              double* __restrict__ lpart) {
    int q = blockIdx.x * 256 + threadIdx.x;
    int o0 = q * 4;
    float4 zev = *(const float4*)(ze + o0);
    const float zv[4] = {zev.x, zev.y, zev.z, zev.w};
    float st4[4], zq4[4];
    double ls = 0.0;
    #pragma unroll
    for (int e = 0; e < 4; ++e) {
        int o = o0 + e;
        int r = (o >> 17) * 1024 + (o & 1023);
        int c = (o >> 10) & 127;
        int j = idxws[r];
        float zq = embed[(size_t)j * K_ + c];
        float st = zv[e] + (zq - zv[e]);
        st4[e] = st; zq4[e] = zq;
        float diff = st - zv[e];
        ls += (double)diff * (double)diff;
    }
    *(float4*)(out_st + o0) = make_float4(st4[0], st4[1], st4[2], st4[3]);
    *(float4*)(out_zq + o0) = make_float4(zq4[0], zq4[1], zq4[2], zq4[3]);
    __shared__ double red[256];
    red[threadIdx.x] = ls;
    __syncthreads();
    for (int s = 128; s; s >>= 1) {
        if (threadIdx.x < s) red[threadIdx.x] += red[threadIdx.x + s];
        __syncthreads();
    }
    if (threadIdx.x == 0) lpart[blockIdx.x] = red[0];
}

// new_cluster_size + sum + loss + exclusive scan of counts (bucket offsets)
__global__ void ema_a_kernel(const float* __restrict__ cluster_size,
                             const int* __restrict__ counts,
                             float* __restrict__ out_ncs, float* __restrict__ nws,
                             const double* __restrict__ lpart, float* __restrict__ out_loss,
                             int* __restrict__ offs) {
    int j = threadIdx.x;                       // 1024 threads
    int cnt = counts[j];
    float ncs = cluster_size[j] * DECAY + ONE_MINUS_DECAY * (float)cnt;
    out_ncs[j] = ncs;
    __shared__ float red[1024];
    __shared__ double dred[1024];
    __shared__ int sc[1024];
    red[j] = ncs;
    sc[j] = cnt;
    double s = 0.0;
    #pragma unroll
    for (int i = 0; i < 4; ++i) s += lpart[j * 4 + i];
    dred[j] = s;
    __syncthreads();
    for (int d = 1; d < 1024; d <<= 1) {       // Hillis-Steele inclusive scan
        int v = (j >= d) ? sc[j - d] : 0;
        __syncthreads();
        sc[j] += v;
        __syncthreads();
    }
    offs[j] = sc[j] - cnt;
    for (int st = 512; st; st >>= 1) {
        if (j < st) { red[j] += red[j + st]; dred[j] += dred[j + st]; }
        __syncthreads();
    }
    if (j == 0) {
        nws[0] = red[0];
        out_loss[0] = (float)((double)BETA * (dred[0] / 4194304.0));
    }
}

// scatter row ids into per-code buckets; LDS-histogram pre-aggregation keeps
// global atomic depth per code <= #blocks (128) regardless of cluster skew.
__global__ void bucket_kernel(const int* __restrict__ idxws, const int* __restrict__ offs,
                              int* __restrict__ cur, int* __restrict__ rows) {
    __shared__ int lcnt[N_];
    __shared__ int lbase[N_];
    int t = threadIdx.x;                       // 256
    #pragma unroll
    for (int i = 0; i < 4; ++i) lcnt[i * 256 + t] = 0;
    __syncthreads();
    int r = blockIdx.x * 256 + t;
    int j = idxws[r];
    atomicAdd(&lcnt[j], 1);                    // LDS atomic
    __syncthreads();
    #pragma unroll
    for (int i = 0; i < 4; ++i) {
        int c = i * 256 + t;
        int n = lcnt[c];
        lbase[c] = n ? atomicAdd(cur + c, n) : 0;
        lcnt[c] = 0;
    }
    __syncthreads();
    int p = atomicAdd(&lcnt[j], 1) + lbase[j];
    rows[offs[j] + p] = r;
}

// load-balanced segmented sum: 64 sorted rows per block, one atomic per
// code-segment boundary (~3/chunk). Immune to cluster-size skew.
__global__ void chunksum_kernel(const float* __restrict__ flat,
                                const int* __restrict__ rows,
                                const int* __restrict__ idxws,
                                float* __restrict__ esum) {
    __shared__ int srid[64];
    __shared__ int scd[65];
    int k = threadIdx.x;                       // 128 threads = K dim
    int b = blockIdx.x;                        // 512 chunks
    if (k < 64) {
        int r = rows[b * 64 + k];
        srid[k] = r;
        scd[k] = idxws[r];
    }
    if (k == 64) scd[64] = -1;                 // sentinel != any code
    __syncthreads();
    float acc = 0.f;
    #pragma unroll 1
    for (int i0 = 0; i0 < 64; i0 += 8) {
        float v[8];
        #pragma unroll
        for (int i = 0; i < 8; ++i)
            v[i] = flat[(size_t)srid[i0 + i] * K_ + k];   // 8 independent loads
        #pragma unroll
        for (int i = 0; i < 8; ++i) {
            acc += v[i];
            int p = i0 + i;
            if (scd[p + 1] != scd[p]) {        // wave-uniform branch
                atomicAdd(esum + (size_t)scd[p] * K_ + k, acc);
                acc = 0.f;
            }
        }
    }
}

// EMA + normalize epilogue on esum
__global__ void ema_b_kernel(const float* __restrict__ embed_avg,
                             const float* __restrict__ esum,
                             const float* __restrict__ out_ncs,
                             const float* __restrict__ nws,
                             float* __restrict__ out_nea, float* __restrict__ out_emb) {
    int o = blockIdx.x * 256 + threadIdx.x;
    int j = o >> 7;
    float navg = embed_avg[o] * DECAY + ONE_MINUS_DECAY * esum[o];
    out_nea[o] = navg;
    float n = nws[0];
    float denom = n + 1024.0f * EPSF;
    float cs = (out_ncs[j] + EPSF) / denom * n;
    float cs_safe = fmaxf(cs, EPSF);
    float v = navg / cs_safe;
    if (v != v) v = 0.f;
    v = fminf(fmaxf(v, -2.f), 2.f);
    out_emb[o] = v;
}

extern "C" void kernel_launch(void* const* d_in, const int* in_sizes, int n_in,
                              void* d_out, int out_size, void* d_ws, size_t ws_size,
                              hipStream_t stream) {
    const float* z_e          = (const float*)d_in[0];
    const float* embed        = (const float*)d_in[1];
    const float* cluster_size = (const float*)d_in[2];
    const float* embed_avg    = (const float*)d_in[3];
    float* out = (float*)d_out;
    char*  ws  = (char*)d_ws;

    float*  flat   = (float*)(ws + WS_FLAT);
    f16*    xhp    = (f16*)  (ws + WS_XH);
    f16*    xlp    = (f16*)  (ws + WS_XL);
    f16*    ehp    = (f16*)  (ws + WS_EH);
    f16*    elp    = (f16*)  (ws + WS_EL);
    float*  nlp    = (float*)(ws + WS_NL);
    float*  p1     = (float*)(ws + WS_P1);
    int*    pi1    = (int*)  (ws + WS_PI1);
    float*  p2     = (float*)(ws + WS_P2);
    int*    pi2    = (int*)  (ws + WS_PI2);
    int*    idxws  = (int*)  (ws + WS_IDX);
    int*    counts = (int*)  (ws + WS_COUNTS);
    int*    cur    = (int*)  (ws + WS_CUR);
    float*  esum   = (float*)(ws + WS_ESUM);
    int*    offs   = (int*)  (ws + WS_OFFS);
    int*    rows   = (int*)  (ws + WS_ROWS);
    double* lpart  = (double*)(ws + WS_LPART);
    float*  nws    = (float*)(ws + WS_NSUM);

    hipMemsetAsync(ws + ZERO_OFF, 0, ZERO_LEN, stream);

    ecvt_kernel<<<N_, 64, 0, stream>>>(embed, ehp, elp, nlp);
    transpose_kernel<<<1024, 256, 0, stream>>>(z_e, flat, xhp, xlp, out + O_ZE);
    nn_kernel<<<dim3(128, 4), 256, 0, stream>>>(xhp, xlp, ehp, elp, nlp, p1, pi1, p2, pi2);
    reduce_refine_kernel<<<M_ / 256, 256, 0, stream>>>(p1, pi1, p2, pi2, flat, embed, nlp,
                                                       idxws, out + O_IDX, counts);
    gather_kernel<<<4096, 256, 0, stream>>>(z_e, embed, idxws,
                                            out + O_ZQST, out + O_ZQ, lpart);
    ema_a_kernel<<<1, 1024, 0, stream>>>(cluster_size, counts, out + O_NCS, nws,
                                         lpart, out + O_LOSS, offs);
    bucket_kernel<<<M_ / 256, 256, 0, stream>>>(idxws, offs, cur, rows);
    chunksum_kernel<<<M_ / 64, K_, 0, stream>>>(flat, rows, idxws, esum);
    ema_b_kernel<<<(N_ * K_) / 256, 256, 0, stream>>>(embed_avg, esum, out + O_NCS, nws,
                                                      out + O_NEA, out + O_EMB);
}